// Round 4
// baseline (100.066 us; speedup 1.0000x reference)
//
#include <hip/hip_runtime.h>
#include <math.h>
#include <stdint.h>

// B=16, R=Hr*Wr=4096, Q=Hq*Wq=1024.
// conf_ref*conf_qry = exp((ar+aq)*x) / (CS_q * RS_r),
//   CS_q = sum_r exp(ar*x), RS_r = sum_q exp(aq*x)  (max-shifts cancel exactly;
//   exp fits fp32 for this data; exact fallback keeps any-data correctness).
// out[r] = exp(0.5*(max_q[(ar+aq)*x - ln CS_q] - ln RS_r))
//
// Pass1 reads x ONCE as a pure stream: thread owns 4 columns, walks 64 rows.
// Col-sums in registers; row-sum partials batched through LDS every 16 rows;
// candidates = float4 groups with max >= th_b (GLOBAL per-batch threshold from
// a sampler kernel) -> rare LDS-atomic compaction. No shuffles/ballots/row
// barriers in the hot loop (round-3 post-mortem: those stalls cost ~2x BW).
// Soundness: non-candidate groups score < s2*th - cmin; checked exactly per
// row in select; full-row re-read fallback on failure/overflow/empty.

constexpr int B = 16;
constexpr int R = 4096;
constexpr int Q = 1024;
constexpr int CAP = 32;
#define DTH 0.70f   // th_b = mean(sampled row maxes) - DTH

__device__ __forceinline__ float wmax64(float v) {
#pragma unroll
    for (int o = 32; o; o >>= 1) v = fmaxf(v, __shfl_xor(v, o, 64));
    return v;
}
__device__ __forceinline__ float max4(float4 v) {
    return fmaxf(fmaxf(v.x, v.y), fmaxf(v.z, v.w));
}

// ---------------- Sampler: th_b = mean of 32 row maxes - DTH ----------------
// One block per batch; 8 threads per sampled row (rows k*128).
__global__ __launch_bounds__(256) void qatm_sample(const float* __restrict__ x,
                                                   float* __restrict__ thArr) {
    const int b = blockIdx.x, t = threadIdx.x;
    const int k = t >> 3, u = t & 7;
    const float4* xr = reinterpret_cast<const float4*>(x) +
                       ((size_t)b * R + (size_t)k * 128) * (Q / 4);
    float m = -INFINITY;
#pragma unroll 8
    for (int i = 0; i < 32; ++i) m = fmaxf(m, max4(xr[u + 8 * i]));
    m = fmaxf(m, __shfl_xor(m, 1, 64));
    m = fmaxf(m, __shfl_xor(m, 2, 64));
    m = fmaxf(m, __shfl_xor(m, 4, 64));
    __shared__ float sm[32];
    if (u == 0) sm[k] = m;
    __syncthreads();
    if (t == 0) {
        float s = 0.f;
#pragma unroll
        for (int i = 0; i < 32; ++i) s += sm[i];
        thArr[b] = s * (1.0f / 32.0f) - DTH;
    }
}

// ---------------- Pass 1: single full stream of x ----------------
// grid B*64; block 256 threads; block (b,chunk) covers rows [chunk*64,+64),
// thread t owns columns [4t, 4t+4) for all 64 rows.
__global__ __launch_bounds__(256) void qatm_pass1(
    const float* __restrict__ x,
    float* __restrict__ psum,        // [B*64][1024] chunk col-sums of exp(ar*x)
    float* __restrict__ rsArr,       // [B*R] row sums of exp(aq*x)
    uint32_t* __restrict__ cntArr,   // [B*R] candidate group count
    float4* __restrict__ cand4,      // [B*R][CAP] candidate float4s
    uint32_t* __restrict__ candg,    // [B*R][CAP] group index (= owning thread)
    const float* __restrict__ thArr,
    const float* __restrict__ coef_ref,
    const float* __restrict__ coef_qry)
{
    const int blk = blockIdx.x;
    const int b = blk >> 6, chunk = blk & 63;
    const int t = threadIdx.x;
    const float ar = coef_ref[0], aq = coef_qry[0];
    const bool same = (ar == aq);            // uniform branch
    const float th = thArr[b];
    const size_t row0 = (size_t)b * R + (size_t)chunk * 64;
    const float4* xb = reinterpret_cast<const float4*>(x) + row0 * (Q / 4) + t;

    __shared__ float ssum[16][256];
    __shared__ int cnt_sh[16];
    if (t < 16) cnt_sh[t] = 0;
    __syncthreads();

    float4 cs = {0.f, 0.f, 0.f, 0.f};

    for (int win = 0; win < 4; ++win) {
#pragma unroll 4
        for (int rr = 0; rr < 16; ++rr) {
            const int r = win * 16 + rr;
            float4 v = xb[(size_t)r * 256];
            float4 e;
            e.x = __expf(ar * v.x); e.y = __expf(ar * v.y);
            e.z = __expf(ar * v.z); e.w = __expf(ar * v.w);
            cs.x += e.x; cs.y += e.y; cs.z += e.z; cs.w += e.w;
            float rp;
            if (same) rp = (e.x + e.y) + (e.z + e.w);
            else rp = (__expf(aq * v.x) + __expf(aq * v.y)) +
                      (__expf(aq * v.z) + __expf(aq * v.w));
            ssum[rr][t] = rp;                 // bank = t%32: 2-way, free
            if (max4(v) >= th) {              // rare (~6 groups / 1024 per row)
                int idx = atomicAdd(&cnt_sh[rr], 1);
                if (idx < CAP) {
                    const size_t grow = row0 + r;
                    cand4[grow * CAP + idx] = v;
                    candg[grow * CAP + idx] = (uint32_t)t;
                }
            }
        }
        __syncthreads();
        // batched row reduce: row slot j = t>>4, segment s = t&15
        const int j = t >> 4, s = t & 15;
        float p = 0.f;
#pragma unroll
        for (int i = 0; i < 16; ++i) p += ssum[j][i * 16 + s];  // 4-way bank, amortized
        p += __shfl_xor(p, 1, 64);
        p += __shfl_xor(p, 2, 64);
        p += __shfl_xor(p, 4, 64);
        p += __shfl_xor(p, 8, 64);
        if (s == 0) {
            const size_t grow = row0 + win * 16 + j;
            rsArr[grow] = p;
            cntArr[grow] = (uint32_t)cnt_sh[j];
            cnt_sh[j] = 0;
        }
        __syncthreads();
    }
    reinterpret_cast<float4*>(psum)[(size_t)blk * 256 + t] = cs;   // coalesced
}

// ---------------- Combine: cvec = ln CS, cmin per batch ----------------
// One block per batch; thread t owns float4 group t.
__global__ __launch_bounds__(256) void qatm_combine(
    const float* __restrict__ psum, float* __restrict__ cvec,
    float* __restrict__ cminArr)
{
    const int b = blockIdx.x, t = threadIdx.x;
    float4 s = {0.f, 0.f, 0.f, 0.f};
    const float4* p = reinterpret_cast<const float4*>(psum) + (size_t)b * 64 * 256 + t;
#pragma unroll 8
    for (int i = 0; i < 64; ++i) {
        float4 v = p[(size_t)i * 256];
        s.x += v.x; s.y += v.y; s.z += v.z; s.w += v.w;
    }
    float4 c;
    c.x = __logf(s.x); c.y = __logf(s.y); c.z = __logf(s.z); c.w = __logf(s.w);
    reinterpret_cast<float4*>(cvec)[b * 256 + t] = c;
    float m = fminf(fminf(c.x, c.y), fminf(c.z, c.w));
    m = -wmax64(-m);
    __shared__ float sh[4];
    if ((t & 63) == 0) sh[t >> 6] = m;
    __syncthreads();
    if (t == 0) cminArr[b] = fminf(fminf(sh[0], sh[1]), fminf(sh[2], sh[3]));
}

// ---------------- Select: candidates + exact soundness check ----------------
__global__ __launch_bounds__(256) void qatm_select(
    const float* __restrict__ x, const float* __restrict__ cvec,
    const float* __restrict__ cminArr, const float* __restrict__ thArr,
    const float* __restrict__ rsArr, const uint32_t* __restrict__ cntArr,
    const float4* __restrict__ cand4, const uint32_t* __restrict__ candg,
    const float* __restrict__ coef_ref, const float* __restrict__ coef_qry,
    float* __restrict__ out)
{
    const int w = threadIdx.x >> 6, l = threadIdx.x & 63;
    const size_t row = (size_t)blockIdx.x * 4 + w;
    const int b = (int)(row >> 12);
    const float ar = coef_ref[0], aq = coef_qry[0], s2 = ar + aq;
    const uint32_t cnt = cntArr[row];
    const float rs = rsArr[row];

    float best = -INFINITY;
    bool fb = (cnt > CAP) || (cnt == 0) || !(s2 > 0.f);
    if (!fb) {
        if (l < (int)cnt) {
            float4 v = cand4[row * CAP + l];
            uint32_t g = candg[row * CAP + l];
            float4 c = reinterpret_cast<const float4*>(cvec)[((size_t)b << 8) + g];
            best = fmaxf(fmaxf(s2 * v.x - c.x, s2 * v.y - c.y),
                         fmaxf(s2 * v.z - c.z, s2 * v.w - c.w));
        }
        best = wmax64(best);
        // non-candidate groups have all x < th -> score < s2*th - cmin
        if (!(best >= s2 * thArr[b] - cminArr[b])) fb = true;
    }
    if (fb) {
        const float4* xr = reinterpret_cast<const float4*>(x) + row * (Q / 4);
        const float4* cq = reinterpret_cast<const float4*>(cvec) + ((size_t)b << 8);
        best = -INFINITY;
#pragma unroll
        for (int it = 0; it < 4; ++it) {
            float4 v = xr[it * 64 + l], c = cq[it * 64 + l];
            best = fmaxf(best, fmaxf(fmaxf(s2 * v.x - c.x, s2 * v.y - c.y),
                                     fmaxf(s2 * v.z - c.z, s2 * v.w - c.w)));
        }
        best = wmax64(best);
    }
    if (l == 0) out[row] = __expf(0.5f * (best - __logf(rs)));
}

extern "C" void kernel_launch(void* const* d_in, const int* in_sizes, int n_in,
                              void* d_out, int out_size, void* d_ws, size_t ws_size,
                              hipStream_t stream) {
    const float* x = (const float*)d_in[0];
    const float* coef_ref = (const float*)d_in[1];
    const float* coef_qry = (const float*)d_in[2];
    float* out = (float*)d_out;

    char* ws = (char*)d_ws;
    // layout (bytes), 16B-aligned:
    //   cand4 : B*R*CAP*16 = 32 MiB
    //   psum  : B*64*1024*4 = 4 MiB
    //   candg : B*R*CAP*4  = 8 MiB
    //   cvec  : B*Q*4      = 64 KiB
    //   rs    : B*R*4      = 256 KiB
    //   cnt   : B*R*4      = 256 KiB
    //   th    : 64 B ; cmin : 64 B
    size_t off = 0;
    float4*   cand4 = (float4*)(ws + off);   off += (size_t)B * R * CAP * 16;
    float*    psum  = (float*)(ws + off);    off += (size_t)B * 64 * 1024 * 4;
    uint32_t* candg = (uint32_t*)(ws + off); off += (size_t)B * R * CAP * 4;
    float*    cvec  = (float*)(ws + off);    off += (size_t)B * Q * 4;
    float*    rsA   = (float*)(ws + off);    off += (size_t)B * R * 4;
    uint32_t* cntA  = (uint32_t*)(ws + off); off += (size_t)B * R * 4;
    float*    thA   = (float*)(ws + off);    off += 64;
    float*    cmin  = (float*)(ws + off);    off += 64;

    qatm_sample<<<B, 256, 0, stream>>>(x, thA);
    qatm_pass1<<<B * 64, 256, 0, stream>>>(x, psum, rsA, cntA, cand4, candg,
                                           thA, coef_ref, coef_qry);
    qatm_combine<<<B, 256, 0, stream>>>(psum, cvec, cmin);
    qatm_select<<<(B * R) / 4, 256, 0, stream>>>(x, cvec, cmin, thA, rsA, cntA,
                                                 cand4, candg, coef_ref, coef_qry, out);
}

// Round 5
// 94.190 us; speedup vs baseline: 1.0624x; 1.0624x over previous
//
#include <hip/hip_runtime.h>
#include <math.h>
#include <stdint.h>

// B=16, R=Hr*Wr=4096, Q=Hq*Wq=1024.
// conf_ref*conf_qry = exp((ar+aq)*x) / (CS_q * RS_r),
//   CS_q = sum_r exp(ar*x), RS_r = sum_q exp(aq*x)  (max-shifts cancel exactly;
//   exp fits fp32 for this data; exact fallback keeps any-data correctness).
// out[r] = exp(0.5*(max_q[(ar+aq)*x - ln CS_q] - ln RS_r))
//
// Pass1 reads x ONCE as a pure stream: thread owns 4 columns, walks 64 rows.
// Col-sums in registers; row-sum partials batched through LDS every 16 rows;
// candidates = float4 groups with max >= th_b (global per-batch threshold from
// 8 sampled row maxes) via rare LDS-atomic compaction. No shuffles/ballots in
// the hot loop. Soundness: non-candidate groups score < s2*th - cmin, checked
// exactly per row in select; 4KB row re-read fallback on failure/overflow.
// Round-4 post-mortem fix: sampler was 16 blocks (serialized ~8-10us before
// pass1) -> now 128 fully-parallel blocks; th computed inline in pass1.

constexpr int B = 16;
constexpr int R = 4096;
constexpr int Q = 1024;
constexpr int CAP = 32;
#define DTH 0.80f   // th_b = mean(8 sampled row maxes) - DTH

__device__ __forceinline__ float wmax64(float v) {
#pragma unroll
    for (int o = 32; o; o >>= 1) v = fmaxf(v, __shfl_xor(v, o, 64));
    return v;
}
__device__ __forceinline__ float max4(float4 v) {
    return fmaxf(fmaxf(v.x, v.y), fmaxf(v.z, v.w));
}

// ---------------- Sampler: rmSamp[b*8+k] = max of row k*512 ----------------
// 128 blocks (one per sampled row), 256 threads = full row in one float4/thread.
__global__ __launch_bounds__(256) void qatm_sample(const float* __restrict__ x,
                                                   float* __restrict__ rmSamp) {
    const int b = blockIdx.x >> 3, k = blockIdx.x & 7;
    const int t = threadIdx.x;
    const float4* xr = reinterpret_cast<const float4*>(x) +
                       ((size_t)b * R + (size_t)k * 512) * (Q / 4);
    float m = wmax64(max4(xr[t]));
    __shared__ float sh[4];
    if ((t & 63) == 0) sh[t >> 6] = m;
    __syncthreads();
    if (t == 0)
        rmSamp[blockIdx.x] = fmaxf(fmaxf(sh[0], sh[1]), fmaxf(sh[2], sh[3]));
}

// ---------------- Pass 1: single full stream of x ----------------
// grid B*64; block (b,chunk) covers rows [chunk*64,+64); thread t owns
// columns [4t,4t+4) for all 64 rows.
__global__ __launch_bounds__(256) void qatm_pass1(
    const float* __restrict__ x,
    float* __restrict__ psum,        // [B*64][1024] chunk col-sums of exp(ar*x)
    float* __restrict__ rsArr,       // [B*R] row sums of exp(aq*x)
    uint32_t* __restrict__ cntArr,   // [B*R] candidate group count
    float4* __restrict__ cand4,      // [B*R][CAP] candidate float4s
    uint32_t* __restrict__ candg,    // [B*R][CAP] group index (= owning thread)
    const float* __restrict__ rmSamp,
    float* __restrict__ thOut,       // [B] published threshold (for select)
    const float* __restrict__ coef_ref,
    const float* __restrict__ coef_qry)
{
    const int blk = blockIdx.x;
    const int b = blk >> 6, chunk = blk & 63;
    const int t = threadIdx.x;
    const float ar = coef_ref[0], aq = coef_qry[0];
    const bool same = (ar == aq);            // uniform branch
    float thsum = 0.f;
#pragma unroll
    for (int i = 0; i < 8; ++i) thsum += rmSamp[b * 8 + i];
    const float th = thsum * 0.125f - DTH;
    if (chunk == 0 && t == 0) thOut[b] = th;

    const size_t row0 = (size_t)b * R + (size_t)chunk * 64;
    const float4* xb = reinterpret_cast<const float4*>(x) + row0 * (Q / 4) + t;

    __shared__ float ssum[16][256];
    __shared__ int cnt_sh[16];
    if (t < 16) cnt_sh[t] = 0;
    __syncthreads();

    float4 cs = {0.f, 0.f, 0.f, 0.f};

    for (int win = 0; win < 4; ++win) {
#pragma unroll 4
        for (int rr = 0; rr < 16; ++rr) {
            const int r = win * 16 + rr;
            float4 v = xb[(size_t)r * 256];
            float4 e;
            e.x = __expf(ar * v.x); e.y = __expf(ar * v.y);
            e.z = __expf(ar * v.z); e.w = __expf(ar * v.w);
            cs.x += e.x; cs.y += e.y; cs.z += e.z; cs.w += e.w;
            float rp;
            if (same) rp = (e.x + e.y) + (e.z + e.w);
            else rp = (__expf(aq * v.x) + __expf(aq * v.y)) +
                      (__expf(aq * v.z) + __expf(aq * v.w));
            ssum[rr][t] = rp;                 // bank = t%32: 2-way, free
            if (max4(v) >= th) {              // rare (~8 groups / 256 threads)
                int idx = atomicAdd(&cnt_sh[rr], 1);
                if (idx < CAP) {
                    const size_t grow = row0 + r;
                    cand4[grow * CAP + idx] = v;
                    candg[grow * CAP + idx] = (uint32_t)t;
                }
            }
        }
        __syncthreads();
        // batched row reduce: row slot j = t>>4, segment s = t&15
        const int j = t >> 4, s = t & 15;
        float p = 0.f;
#pragma unroll
        for (int i = 0; i < 16; ++i) p += ssum[j][i * 16 + s];
        p += __shfl_xor(p, 1, 64);
        p += __shfl_xor(p, 2, 64);
        p += __shfl_xor(p, 4, 64);
        p += __shfl_xor(p, 8, 64);
        if (s == 0) {
            const size_t grow = row0 + win * 16 + j;
            rsArr[grow] = p;
            cntArr[grow] = (uint32_t)cnt_sh[j];
            cnt_sh[j] = 0;
        }
        __syncthreads();
    }
    reinterpret_cast<float4*>(psum)[(size_t)blk * 256 + t] = cs;   // coalesced
}

// ---------------- Combine: cvec = ln CS, cmin per batch ----------------
__global__ __launch_bounds__(256) void qatm_combine(
    const float* __restrict__ psum, float* __restrict__ cvec,
    float* __restrict__ cminArr)
{
    const int b = blockIdx.x, t = threadIdx.x;
    float4 s = {0.f, 0.f, 0.f, 0.f};
    const float4* p = reinterpret_cast<const float4*>(psum) + (size_t)b * 64 * 256 + t;
#pragma unroll 16
    for (int i = 0; i < 64; ++i) {
        float4 v = p[(size_t)i * 256];
        s.x += v.x; s.y += v.y; s.z += v.z; s.w += v.w;
    }
    float4 c;
    c.x = __logf(s.x); c.y = __logf(s.y); c.z = __logf(s.z); c.w = __logf(s.w);
    reinterpret_cast<float4*>(cvec)[b * 256 + t] = c;
    float m = fminf(fminf(c.x, c.y), fminf(c.z, c.w));
    m = -wmax64(-m);
    __shared__ float sh[4];
    if ((t & 63) == 0) sh[t >> 6] = m;
    __syncthreads();
    if (t == 0) cminArr[b] = fminf(fminf(sh[0], sh[1]), fminf(sh[2], sh[3]));
}

// ---------------- Select: candidates + exact soundness check ----------------
__global__ __launch_bounds__(256) void qatm_select(
    const float* __restrict__ x, const float* __restrict__ cvec,
    const float* __restrict__ cminArr, const float* __restrict__ thArr,
    const float* __restrict__ rsArr, const uint32_t* __restrict__ cntArr,
    const float4* __restrict__ cand4, const uint32_t* __restrict__ candg,
    const float* __restrict__ coef_ref, const float* __restrict__ coef_qry,
    float* __restrict__ out)
{
    const int w = threadIdx.x >> 6, l = threadIdx.x & 63;
    const size_t row = (size_t)blockIdx.x * 4 + w;
    const int b = (int)(row >> 12);
    const float ar = coef_ref[0], aq = coef_qry[0], s2 = ar + aq;
    const uint32_t cnt = cntArr[row];
    const float rs = rsArr[row];

    float best = -INFINITY;
    bool fb = (cnt > CAP) || (cnt == 0) || !(s2 > 0.f);
    if (!fb) {
        if (l < (int)cnt) {
            float4 v = cand4[row * CAP + l];
            uint32_t g = candg[row * CAP + l];
            float4 c = reinterpret_cast<const float4*>(cvec)[((size_t)b << 8) + g];
            best = fmaxf(fmaxf(s2 * v.x - c.x, s2 * v.y - c.y),
                         fmaxf(s2 * v.z - c.z, s2 * v.w - c.w));
        }
        best = wmax64(best);
        // non-candidate groups have all x < th -> score < s2*th - cmin
        if (!(best >= s2 * thArr[b] - cminArr[b])) fb = true;
    }
    if (fb) {
        const float4* xr = reinterpret_cast<const float4*>(x) + row * (Q / 4);
        const float4* cq = reinterpret_cast<const float4*>(cvec) + ((size_t)b << 8);
        best = -INFINITY;
#pragma unroll
        for (int it = 0; it < 4; ++it) {
            float4 v = xr[it * 64 + l], c = cq[it * 64 + l];
            best = fmaxf(best, fmaxf(fmaxf(s2 * v.x - c.x, s2 * v.y - c.y),
                                     fmaxf(s2 * v.z - c.z, s2 * v.w - c.w)));
        }
        best = wmax64(best);
    }
    if (l == 0) out[row] = __expf(0.5f * (best - __logf(rs)));
}

extern "C" void kernel_launch(void* const* d_in, const int* in_sizes, int n_in,
                              void* d_out, int out_size, void* d_ws, size_t ws_size,
                              hipStream_t stream) {
    const float* x = (const float*)d_in[0];
    const float* coef_ref = (const float*)d_in[1];
    const float* coef_qry = (const float*)d_in[2];
    float* out = (float*)d_out;

    char* ws = (char*)d_ws;
    // layout (bytes), 16B-aligned:
    //   cand4 : B*R*CAP*16 = 32 MiB
    //   psum  : B*64*1024*4 = 4 MiB
    //   candg : B*R*CAP*4  = 8 MiB
    //   cvec  : B*Q*4      = 64 KiB
    //   rs    : B*R*4      = 256 KiB
    //   cnt   : B*R*4      = 256 KiB
    //   rmSamp: 512 B ; th : 64 B ; cmin : 64 B
    size_t off = 0;
    float4*   cand4 = (float4*)(ws + off);   off += (size_t)B * R * CAP * 16;
    float*    psum  = (float*)(ws + off);    off += (size_t)B * 64 * 1024 * 4;
    uint32_t* candg = (uint32_t*)(ws + off); off += (size_t)B * R * CAP * 4;
    float*    cvec  = (float*)(ws + off);    off += (size_t)B * Q * 4;
    float*    rsA   = (float*)(ws + off);    off += (size_t)B * R * 4;
    uint32_t* cntA  = (uint32_t*)(ws + off); off += (size_t)B * R * 4;
    float*    rmSamp= (float*)(ws + off);    off += 512;
    float*    thA   = (float*)(ws + off);    off += 64;
    float*    cmin  = (float*)(ws + off);    off += 64;

    qatm_sample<<<B * 8, 256, 0, stream>>>(x, rmSamp);
    qatm_pass1<<<B * 64, 256, 0, stream>>>(x, psum, rsA, cntA, cand4, candg,
                                           rmSamp, thA, coef_ref, coef_qry);
    qatm_combine<<<B, 256, 0, stream>>>(psum, cvec, cmin);
    qatm_select<<<(B * R) / 4, 256, 0, stream>>>(x, cvec, cmin, thA, rsA, cntA,
                                                 cand4, candg, coef_ref, coef_qry, out);
}

// Round 7
// 88.947 us; speedup vs baseline: 1.1250x; 1.0589x over previous
//
#include <hip/hip_runtime.h>
#include <math.h>
#include <stdint.h>

// B=16, R=Hr*Wr=4096, Q=Hq*Wq=1024.
// conf_ref*conf_qry = exp((ar+aq)*x) / (CS_q * RS_r),
//   CS_q = sum_r exp(ar*x), RS_r = sum_q exp(aq*x)  (max-shifts cancel exactly;
//   exp fits fp32 for this data; exact fallback keeps any-data correctness).
// out[r] = exp(0.5*(max_q[(ar+aq)*x - ln CS_q] - ln RS_r))
//
// Pass1 streams x ONCE (nontemporal, 8 loads in flight): thread owns 4 cols,
// walks 64 rows. Col-sums in registers; row-sums batched through LDS every 16
// rows; candidates = float4 groups with max >= th_b (per-batch threshold from
// 8 sampled row maxes). Soundness: non-candidate groups score < s2*th - cmin,
// checked exactly per row in select; 4KB row re-read fallback.
// Round-6 fix: __builtin_nontemporal_load needs a native vector type, not
// HIP_vector_type -> load via ext_vector_type(4) alias.

constexpr int B = 16;
constexpr int R = 4096;
constexpr int Q = 1024;
constexpr int CAP = 32;
#define DTH 0.80f   // th_b = mean(8 sampled row maxes) - DTH

typedef float float4n __attribute__((ext_vector_type(4)));

__device__ __forceinline__ float wmax64(float v) {
#pragma unroll
    for (int o = 32; o; o >>= 1) v = fmaxf(v, __shfl_xor(v, o, 64));
    return v;
}
__device__ __forceinline__ float max4(float4 v) {
    return fmaxf(fmaxf(v.x, v.y), fmaxf(v.z, v.w));
}
// order-preserving float<->uint for atomicMin on floats (any sign)
__device__ __forceinline__ uint32_t encf(float f) {
    uint32_t u = __float_as_uint(f);
    return (u & 0x80000000u) ? ~u : (u | 0x80000000u);
}
__device__ __forceinline__ float decf(uint32_t e) {
    uint32_t u = (e & 0x80000000u) ? (e & 0x7FFFFFFFu) : ~e;
    return __uint_as_float(u);
}

// ---------------- Sampler: rmSamp[b*8+k] = max of row k*512; init cminEnc ---
__global__ __launch_bounds__(256) void qatm_sample(const float* __restrict__ x,
                                                   float* __restrict__ rmSamp,
                                                   uint32_t* __restrict__ cminEnc) {
    const int blk = blockIdx.x;
    const int b = blk >> 3, k = blk & 7;
    const int t = threadIdx.x;
    if ((blk & 7) == 0 && t == 0) cminEnc[b] = 0xFFFFFFFFu;
    const float4* xr = reinterpret_cast<const float4*>(x) +
                       ((size_t)b * R + (size_t)k * 512) * (Q / 4);
    float m = wmax64(max4(xr[t]));
    __shared__ float sh[4];
    if ((t & 63) == 0) sh[t >> 6] = m;
    __syncthreads();
    if (t == 0)
        rmSamp[blk] = fmaxf(fmaxf(sh[0], sh[1]), fmaxf(sh[2], sh[3]));
}

// ---------------- Pass 1: single full stream of x ----------------
// grid B*64; block (b,chunk) covers rows [chunk*64,+64); thread t owns
// columns [4t,4t+4) for all 64 rows. 8-deep explicit load pipeline.
__global__ __launch_bounds__(256) void qatm_pass1(
    const float* __restrict__ x,
    float* __restrict__ psum,        // [B*64][1024] chunk col-sums of exp(ar*x)
    float2* __restrict__ rscnt,      // [B*R] (row sum, count bits)
    float4* __restrict__ cand4,      // [B*R][CAP] candidate float4s
    uint32_t* __restrict__ candg,    // [B*R][CAP] group index (= owning thread)
    const float* __restrict__ rmSamp,
    float* __restrict__ thOut,       // [B] published threshold (for select)
    const float* __restrict__ coef_ref,
    const float* __restrict__ coef_qry)
{
    const int blk = blockIdx.x;
    const int b = blk >> 6, chunk = blk & 63;
    const int t = threadIdx.x;
    const float ar = coef_ref[0], aq = coef_qry[0];
    const bool same = (ar == aq);            // uniform branch
    float thsum = 0.f;
#pragma unroll
    for (int i = 0; i < 8; ++i) thsum += rmSamp[b * 8 + i];
    const float th = thsum * 0.125f - DTH;
    if (chunk == 0 && t == 0) thOut[b] = th;

    const size_t row0 = (size_t)b * R + (size_t)chunk * 64;
    const float4n* xb = reinterpret_cast<const float4n*>(x) + row0 * (Q / 4) + t;

    __shared__ float ssum[16][256];
    __shared__ int cnt_sh[16];
    if (t < 16) cnt_sh[t] = 0;
    __syncthreads();

    float4 cs = {0.f, 0.f, 0.f, 0.f};

    for (int win = 0; win < 4; ++win) {
        const float4n* xw = xb + (size_t)win * 16 * 256;
#pragma unroll
        for (int rr8 = 0; rr8 < 16; rr8 += 8) {
            float4n vn[8];
#pragma unroll
            for (int k = 0; k < 8; ++k)
                vn[k] = __builtin_nontemporal_load(&xw[(size_t)(rr8 + k) * 256]);
#pragma unroll
            for (int k = 0; k < 8; ++k) {
                const int rr = rr8 + k;
                float4 v = make_float4(vn[k].x, vn[k].y, vn[k].z, vn[k].w);
                float4 e;
                e.x = __expf(ar * v.x); e.y = __expf(ar * v.y);
                e.z = __expf(ar * v.z); e.w = __expf(ar * v.w);
                cs.x += e.x; cs.y += e.y; cs.z += e.z; cs.w += e.w;
                float rp;
                if (same) rp = (e.x + e.y) + (e.z + e.w);
                else rp = (__expf(aq * v.x) + __expf(aq * v.y)) +
                          (__expf(aq * v.z) + __expf(aq * v.w));
                ssum[rr][t] = rp;             // bank = t%32: 2-way, free
                if (max4(v) >= th) {          // rare (~8 of 256 threads/row)
                    int idx = atomicAdd(&cnt_sh[rr], 1);
                    if (idx < CAP) {
                        const size_t grow = row0 + win * 16 + rr;
                        cand4[grow * CAP + idx] = v;
                        candg[grow * CAP + idx] = (uint32_t)t;
                    }
                }
            }
        }
        __syncthreads();
        // batched row reduce: row slot j = t>>4, segment s = t&15
        const int j = t >> 4, s = t & 15;
        float p = 0.f;
#pragma unroll
        for (int i = 0; i < 16; ++i) p += ssum[j][i * 16 + s];
        p += __shfl_xor(p, 1, 64);
        p += __shfl_xor(p, 2, 64);
        p += __shfl_xor(p, 4, 64);
        p += __shfl_xor(p, 8, 64);
        if (s == 0) {
            const size_t grow = row0 + win * 16 + j;
            rscnt[grow] = make_float2(p, __uint_as_float((uint32_t)cnt_sh[j]));
            cnt_sh[j] = 0;
        }
        __syncthreads();
    }
    reinterpret_cast<float4*>(psum)[(size_t)blk * 256 + t] = cs;   // coalesced
}

// ---------------- Combine: cvec = ln CS; cmin via atomicMin ----------------
// grid 64: block j covers batch j>>2, cols (j&3)*256 + t. Coalesced 1KB reads.
__global__ __launch_bounds__(256) void qatm_combine(
    const float* __restrict__ psum, float* __restrict__ cvec,
    uint32_t* __restrict__ cminEnc)
{
    const int b = blockIdx.x >> 2, part = blockIdx.x & 3;
    const int t = threadIdx.x;
    const int col = part * 256 + t;
    float s = 0.f;
    const float* p = psum + (size_t)b * 64 * 1024 + col;
#pragma unroll 16
    for (int i = 0; i < 64; ++i) s += p[(size_t)i * 1024];
    const float c = __logf(s);
    cvec[b * 1024 + col] = c;
    float m = -wmax64(-c);
    __shared__ float sh[4];
    if ((t & 63) == 0) sh[t >> 6] = m;
    __syncthreads();
    if (t == 0) {
        float mm = fminf(fminf(sh[0], sh[1]), fminf(sh[2], sh[3]));
        atomicMin(&cminEnc[b], encf(mm));
    }
}

// ---------------- Select: candidates + exact soundness check ----------------
__global__ __launch_bounds__(256) void qatm_select(
    const float* __restrict__ x, const float* __restrict__ cvec,
    const uint32_t* __restrict__ cminEnc, const float* __restrict__ thArr,
    const float2* __restrict__ rscnt,
    const float4* __restrict__ cand4, const uint32_t* __restrict__ candg,
    const float* __restrict__ coef_ref, const float* __restrict__ coef_qry,
    float* __restrict__ out)
{
    const int w = threadIdx.x >> 6, l = threadIdx.x & 63;
    const size_t row = (size_t)blockIdx.x * 4 + w;
    const int b = (int)(row >> 12);
    const float ar = coef_ref[0], aq = coef_qry[0], s2 = ar + aq;
    const float2 rc = rscnt[row];
    const float rs = rc.x;
    const uint32_t cnt = __float_as_uint(rc.y);

    float best = -INFINITY;
    bool fb = (cnt > CAP) || (cnt == 0) || !(s2 > 0.f);
    if (!fb) {
        if (l < (int)cnt) {
            float4 v = cand4[row * CAP + l];
            uint32_t g = candg[row * CAP + l];
            float4 c = reinterpret_cast<const float4*>(cvec)[((size_t)b << 8) + g];
            best = fmaxf(fmaxf(s2 * v.x - c.x, s2 * v.y - c.y),
                         fmaxf(s2 * v.z - c.z, s2 * v.w - c.w));
        }
        best = wmax64(best);
        // non-candidate groups have all x < th -> score < s2*th - cmin
        if (!(best >= s2 * thArr[b] - decf(cminEnc[b]))) fb = true;
    }
    if (fb) {
        const float4* xr = reinterpret_cast<const float4*>(x) + row * (Q / 4);
        const float4* cq = reinterpret_cast<const float4*>(cvec) + ((size_t)b << 8);
        best = -INFINITY;
#pragma unroll
        for (int it = 0; it < 4; ++it) {
            float4 v = xr[it * 64 + l], c = cq[it * 64 + l];
            best = fmaxf(best, fmaxf(fmaxf(s2 * v.x - c.x, s2 * v.y - c.y),
                                     fmaxf(s2 * v.z - c.z, s2 * v.w - c.w)));
        }
        best = wmax64(best);
    }
    if (l == 0) out[row] = __expf(0.5f * (best - __logf(rs)));
}

extern "C" void kernel_launch(void* const* d_in, const int* in_sizes, int n_in,
                              void* d_out, int out_size, void* d_ws, size_t ws_size,
                              hipStream_t stream) {
    const float* x = (const float*)d_in[0];
    const float* coef_ref = (const float*)d_in[1];
    const float* coef_qry = (const float*)d_in[2];
    float* out = (float*)d_out;

    char* ws = (char*)d_ws;
    // layout (bytes), 16B-aligned:
    //   cand4 : B*R*CAP*16 = 32 MiB
    //   psum  : B*64*1024*4 = 4 MiB
    //   candg : B*R*CAP*4  = 8 MiB
    //   cvec  : B*Q*4      = 64 KiB
    //   rscnt : B*R*8      = 512 KiB
    //   rmSamp: 512 B ; th : 64 B ; cminEnc : 64 B
    size_t off = 0;
    float4*   cand4 = (float4*)(ws + off);   off += (size_t)B * R * CAP * 16;
    float*    psum  = (float*)(ws + off);    off += (size_t)B * 64 * 1024 * 4;
    uint32_t* candg = (uint32_t*)(ws + off); off += (size_t)B * R * CAP * 4;
    float*    cvec  = (float*)(ws + off);    off += (size_t)B * Q * 4;
    float2*   rscnt = (float2*)(ws + off);   off += (size_t)B * R * 8;
    float*    rmSamp= (float*)(ws + off);    off += 512;
    float*    thA   = (float*)(ws + off);    off += 64;
    uint32_t* cminE = (uint32_t*)(ws + off); off += 64;

    qatm_sample<<<B * 8, 256, 0, stream>>>(x, rmSamp, cminE);
    qatm_pass1<<<B * 64, 256, 0, stream>>>(x, psum, rscnt, cand4, candg,
                                           rmSamp, thA, coef_ref, coef_qry);
    qatm_combine<<<64, 256, 0, stream>>>(psum, cvec, cminE);
    qatm_select<<<(B * R) / 4, 256, 0, stream>>>(x, cvec, cminE, thA, rscnt,
                                                 cand4, candg, coef_ref, coef_qry, out);
}